// Round 10
// baseline (267.370 us; speedup 1.0000x reference)
//
#include <hip/hip_runtime.h>

typedef __bf16 bf16_t;
typedef __bf16 bf16x2 __attribute__((ext_vector_type(2)));
typedef __bf16 bf16x4 __attribute__((ext_vector_type(4)));
typedef __bf16 bf16x8 __attribute__((ext_vector_type(8)));
typedef float floatx4 __attribute__((ext_vector_type(4)));

// async 16B/lane global->LDS (bf16 operands only). Dest = wave-uniform base + lane*16.
__device__ __forceinline__ void gll16(const void* g, void* l) {
  __builtin_amdgcn_global_load_lds(
      (const __attribute__((address_space(1))) void*)g,
      (__attribute__((address_space(3))) void*)l, 16, 0, 0);
}

__device__ __forceinline__ bf16x8 cvt8(const float4 a, const float4 b) {
  bf16x8 v;
  v[0] = (bf16_t)a.x; v[1] = (bf16_t)a.y; v[2] = (bf16_t)a.z; v[3] = (bf16_t)a.w;
  v[4] = (bf16_t)b.x; v[5] = (bf16_t)b.y; v[6] = (bf16_t)b.z; v[7] = (bf16_t)b.w;
  return v;
}

// ---------------------------------------------------------------------------
// fp32 -> bf16 for all three operands in ONE launch.
// blocks [0,4096) -> x, [4096,5632) -> w_qkv, [5632,6144) -> w_out.
// ---------------------------------------------------------------------------
__global__ __launch_bounds__(256)
void cvt_all(const float* __restrict__ x,  bf16_t* __restrict__ xb,
             const float* __restrict__ wq, bf16_t* __restrict__ wqb,
             const float* __restrict__ wo, bf16_t* __restrict__ wob)
{
  const int bid = blockIdx.x;
  const float* s;
  bf16_t* d;
  int i;
  if (bid < 4096)      { s = x;  d = xb;  i = bid * 256 + threadIdx.x; }
  else if (bid < 5632) { s = wq; d = wqb; i = (bid - 4096) * 256 + threadIdx.x; }
  else                 { s = wo; d = wob; i = (bid - 5632) * 256 + threadIdx.x; }
  const float4 a = ((const float4*)s)[2 * i];
  const float4 b = ((const float4*)s)[2 * i + 1];
  *(bf16x8*)(d + (size_t)i * 8) = cvt8(a, b);
}

// ---------------------------------------------------------------------------
// GEMM: C[M,Nf] = A[M,K] * W[Nf,K]^T (+bias), fp32 accum, bf16 MFMA.
// Round-18: tile geometry attack. r4/r7/r8 (three different schedules) all
//   landed at the same time -> schedule is NOT the limiter; per-MFMA LDS
//   traffic is (48 KB LDS port traffic per 64 block-MFMAs = ~5:1 LDS:MFMA
//   oversubscription). Fix: BM=128, BN=256, wave tile 64x128 -> 32 MFMA per
//   12 ds_read_b128 (-27% LDS bytes/MFMA, -25% DMA bytes/MFMA).
//   Schedule = r8's PASSING counted-vmcnt 3-buf pipeline, params adjusted:
//   stage = 6 gll16/thread (A 2 + B 4) -> steady wait vmcnt(6), tail vmcnt(0).
//   LDS 3 x 24 KB = 72 KB -> 2 blocks/CU. acc 4x8 floatx4.
// ---------------------------------------------------------------------------
template<bool C32>
__global__ __launch_bounds__(256, 2)
void gemm_bt(const bf16_t* __restrict__ Ab, const bf16_t* __restrict__ Wb,
             const float* __restrict__ bias, void* __restrict__ Cv,
             int M, int Nf, int K, int lda, int qcols, float qscale)
{
  __shared__ __align__(16) bf16_t lA[3][128 * 32];
  __shared__ __align__(16) bf16_t lB[3][256 * 32];

  const int tid  = threadIdx.x;
  const int wave = tid >> 6;
  const int lane = tid & 63;
  const int q    = lane >> 4;
  const int ln   = lane & 15;
  const int wm   = wave >> 1, wn = wave & 1;

  // XCD mapping: x = hw XCD (blockIdx%8). XCD x owns mt in [x*8, x*8+8),
  // nt-major inside. GEMM1: 64mt x 12nt = 768 blocks; GEMM2: 64 x 4 = 256.
  const int x     = blockIdx.x & 7;
  const int local = blockIdx.x >> 3;
  const int mt = x * 8 + (local & 7);
  const int nt = local >> 3;
  const int m0 = mt << 7, n0 = nt << 8;

  const int kiters = K >> 5;

  // staging: 6 gll16/thread per tile (A 2 + B 4); LDS chunk layout
  // c' = c ^ ((r>>1)&3)  (r3's proven BK=32 pattern).
  auto stage = [&](int buf, int k0s) {
#pragma unroll
    for (int tt = 0; tt < 2; ++tt) {
      const int rbase = tt * 64 + wave * 16;
      const int r  = rbase + (lane >> 2);
      const int gc = (lane & 3) ^ ((r >> 1) & 3);
      gll16(Ab + (size_t)(m0 + r) * lda + k0s + gc * 8, lA[buf] + rbase * 32);
    }
#pragma unroll
    for (int tt = 0; tt < 4; ++tt) {
      const int rbase = tt * 64 + wave * 16;
      const int r  = rbase + (lane >> 2);
      const int gc = (lane & 3) ^ ((r >> 1) & 3);
      gll16(Wb + (size_t)(n0 + r) * K + k0s + gc * 8, lB[buf] + rbase * 32);
    }
  };

  floatx4 acc[4][8] = {};

  stage(0, 0);
  stage(1, 32);

  for (int t = 0; t < kiters; ++t) {
    const int buf = t % 3;

    // counted wait: stage(t)'s 6 loads retired (in-order), stage(t+1)'s 6
    // may remain in flight ACROSS the barrier. Last iter: full drain.
    if (t + 1 < kiters) {
      asm volatile("s_waitcnt vmcnt(6)" ::: "memory");
    } else {
      asm volatile("s_waitcnt vmcnt(0)" ::: "memory");
    }
    __builtin_amdgcn_sched_barrier(0);
    __builtin_amdgcn_s_barrier();
    __builtin_amdgcn_sched_barrier(0);

    bf16x8 af[4], bfr[8];
#pragma unroll
    for (int i = 0; i < 4; ++i) {
      const int r = wm * 64 + i * 16 + ln;
      af[i] = *(const bf16x8*)(lA[buf] + r * 32 + (q ^ ((r >> 1) & 3)) * 8);
    }
#pragma unroll
    for (int j = 0; j < 8; ++j) {
      const int r = wn * 128 + j * 16 + ln;
      bfr[j] = *(const bf16x8*)(lB[buf] + r * 32 + (q ^ ((r >> 1) & 3)) * 8);
    }
    __builtin_amdgcn_s_setprio(1);
#pragma unroll
    for (int i = 0; i < 4; ++i)
#pragma unroll
      for (int j = 0; j < 8; ++j)
        acc[i][j] = __builtin_amdgcn_mfma_f32_16x16x32_bf16(af[i], bfr[j], acc[i][j], 0, 0, 0);
    __builtin_amdgcn_s_setprio(0);

    // depth-2 prefetch into buf[(t+2)%3] (= buf[(t-1)%3], whose readers all
    // passed barrier(t) with completed reads).
    if (t + 2 < kiters) stage((t + 2) % 3, (t + 2) << 5);
  }

  // epilogue: C/D layout col=lane&15, row=(lane>>4)*4+reg
#pragma unroll
  for (int j = 0; j < 8; ++j) {
    const int col = n0 + wn * 128 + j * 16 + ln;
    const float bv = bias ? bias[col] : 0.0f;
    const float sc = (col < qcols) ? qscale : 1.0f;
#pragma unroll
    for (int i = 0; i < 4; ++i) {
      const int row = m0 + wm * 64 + i * 16 + q * 4;
#pragma unroll
      for (int r = 0; r < 4; ++r) {
        const float val = acc[i][j][r] * sc + bv;
        if constexpr (C32)
          ((float*)Cv)[(size_t)(row + r) * Nf + col] = val;
        else
          ((bf16_t*)Cv)[(size_t)(row + r) * Nf + col] = (bf16_t)val;
      }
    }
  }
}

// ---------------------------------------------------------------------------
// Attention, in-place on bf16 qkv (Q pre-scaled by softmax scale * log2e).
// UNCHANGED from round 7/8 (passing, ~99 us).
// ---------------------------------------------------------------------------
__global__ __launch_bounds__(256, 2)
void attn_kernel(bf16_t* __restrict__ qkv)
{
  __shared__ __align__(16) bf16_t lK[2][128 * 64]; // K tile dbuf [128 tok][64 d]
  __shared__ __align__(16) bf16_t lVT[64 * 128];   // V^T [64 d][128 tok], chunk^(d&7)
  __shared__ __align__(16) bf16_t lP[128 * 128];   // P [m][tok], chunk^(m&7); head = Q staging

  const int tid  = threadIdx.x;
  const int wave = tid >> 6;
  const int lane = tid & 63;
  const int q  = lane >> 4;
  const int ln = lane & 15;
  const int wm = wave >> 1, wn = wave & 1;

  // XCD swizzle: hw%8 = XCD; give each XCD 128 consecutive work-ids
  // (= all 16 q-tiles of 8 heads -> K/V working set 4MB = one L2).
  const int hw = blockIdx.x;
  const int w  = (hw & 7) * 128 + (hw >> 3);
  const int qt = w & 15;
  const int h  = (w >> 4) & 15;
  const int b  = w >> 8;

  bf16_t* Qbase = qkv + (size_t)(b * 2048 + qt * 128) * 3072 + h * 64;  // also O dest
  const bf16_t* Kbase = qkv + (size_t)(b * 2048) * 3072 + 1024 + h * 64;
  const bf16_t* Vbase = qkv + (size_t)(b * 2048) * 3072 + 2048 + h * 64;

  // ---- prologue: stage Q into lP head (flat [128][64], chunk^(r&7)) + K[0]
#pragma unroll
  for (int t = 0; t < 4; ++t) {
    const int rbase = t * 32 + wave * 8;
    const int r  = rbase + (lane >> 3);
    const int gc = (lane & 7) ^ (r & 7);
    gll16(Qbase + (size_t)r * 3072 + gc * 8, lP + rbase * 64);
    gll16(Kbase + (size_t)r * 3072 + gc * 8, lK[0] + rbase * 64);
  }
  __syncthreads();

  bf16x8 qf[4][2];  // Q[m][d] fragments; used as MFMA B-operand (Q^T[d][m])
#pragma unroll
  for (int i = 0; i < 4; ++i) {
    const int r = wm * 64 + i * 16 + ln;
#pragma unroll
    for (int kt = 0; kt < 2; ++kt) {
      const int c = (kt * 4 + q) ^ (r & 7);
      qf[i][kt] = *(const bf16x8*)(lP + r * 64 + c * 8);
    }
  }
  // (no barrier needed here: iter-0's top barrier orders qf reads vs lP reuse)

  // V[0] into regs (token pair 2*lane, 2*lane+1; d-chunks wave + it*4)
  bf16x8 vcur[2][2], vnxt[2][2];
#pragma unroll
  for (int it = 0; it < 2; ++it) {
    const bf16_t* src = Vbase + (size_t)(2 * lane) * 3072 + (wave + it * 4) * 8;
    vcur[it][0] = *(const bf16x8*)src;
    vcur[it][1] = *(const bf16x8*)(src + 3072);
  }

  floatx4 accO[2][4] = {};  // [m-tile i][d-tile n]
  floatx4 accS[2] = {};     // row sums via ones-column MFMA (deduped: 1x per m-row)

  bf16x8 ones;
#pragma unroll
  for (int j = 0; j < 8; ++j) ones[j] = (bf16_t)1.0f;

  for (int jt = 0; jt < 16; ++jt) {
    const bf16_t* lKc = lK[jt & 1];
    bf16_t*       lKn = lK[(jt & 1) ^ 1];

    // syncA: prev-iter PV reads of lVT/lP done; lK[cur] gll16 + vcur loads
    // (issued one phase ago) complete here via the in-order vmcnt chain
    // (vcur register loads were issued after the K DMAs).
    __syncthreads();

    // scatter vcur -> lVT[d][tok], tok-chunk ch = (tok>>3)^(d&7)
#pragma unroll
    for (int it = 0; it < 2; ++it) {
      const int c = wave + it * 4;
#pragma unroll
      for (int j = 0; j < 8; ++j) {
        const int d  = c * 8 + j;
        const int ch = (lane >> 2) ^ (d & 7);
        bf16x2 pr;
        pr[0] = vcur[it][0][j];
        pr[1] = vcur[it][1][j];
        *(bf16x2*)(lVT + d * 128 + ch * 8 + ((2 * lane) & 7)) = pr;
      }
    }

    // K fragments from current buffer
    bf16x8 kf[4][2];
#pragma unroll
    for (int n = 0; n < 4; ++n) {
      const int r = wn * 64 + n * 16 + ln;
#pragma unroll
      for (int kt = 0; kt < 2; ++kt) {
        const int c = (kt * 4 + q) ^ (r & 7);
        kf[n][kt] = *(const bf16x8*)(lKc + r * 64 + c * 8);
      }
    }

    // ---- prefetch tile jt+1: K -> lK[nxt] (async DMA), V -> regs.
    // Drained at syncB, after the S^T phase -> latency mostly hidden.
    if (jt < 15) {
      const int j0n = (jt + 1) * 128;
#pragma unroll
      for (int t = 0; t < 4; ++t) {
        const int rbase = t * 32 + wave * 8;
        const int r  = rbase + (lane >> 3);
        const int gc = (lane & 7) ^ (r & 7);
        gll16(Kbase + (size_t)(j0n + r) * 3072 + gc * 8, lKn + rbase * 64);
      }
#pragma unroll
      for (int it = 0; it < 2; ++it) {
        const bf16_t* src = Vbase + (size_t)(j0n + 2 * lane) * 3072 + (wave + it * 4) * 8;
        vnxt[it][0] = *(const bf16x8*)src;
        vnxt[it][1] = *(const bf16x8*)(src + 3072);
      }
    }

    // ---- S^T = K Q^T  (wave: toks [wn*64,+64) x m [wm*64,+64))
    __builtin_amdgcn_s_setprio(1);
#pragma unroll
    for (int i = 0; i < 4; ++i) {      // tok-tile
#pragma unroll
      for (int n = 0; n < 4; ++n) {    // m-tile
        floatx4 st = {0.0f, 0.0f, 0.0f, 0.0f};
        st = __builtin_amdgcn_mfma_f32_16x16x32_bf16(kf[i][0], qf[n][0], st, 0, 0, 0);
        st = __builtin_amdgcn_mfma_f32_16x16x32_bf16(kf[i][1], qf[n][1], st, 0, 0, 0);
        // lane holds S^T[tok = wn*64+i*16+q*4+r][m = wm*64+n*16+ln], r=0..3
        // Q pre-scaled by GEMM1 epilogue -> exp2 direct.
        bf16x4 pk;
#pragma unroll
        for (int r = 0; r < 4; ++r)
          pk[r] = (bf16_t)__builtin_amdgcn_exp2f(st[r]);
        const int m    = wm * 64 + n * 16 + ln;
        const int tok0 = wn * 64 + i * 16 + q * 4;
        *(bf16x4*)(lP + m * 128 + (((tok0 >> 3) ^ (m & 7)) << 3) + (tok0 & 7)) = pk;
      }
    }
    __builtin_amdgcn_s_setprio(0);

    // syncB: lP + lVT visible to all waves (also drains prefetches -- mostly
    // complete after the S^T phase above).
    __syncthreads();

    // ---- O += P * V ; rowsum += P * 1
    // m-split: wave owns m in [wave*32, +32), all 64 d. accS deduped.
    __builtin_amdgcn_s_setprio(1);
#pragma unroll
    for (int ks = 0; ks < 4; ++ks) {
      bf16x8 bv[4];
#pragma unroll
      for (int n = 0; n < 4; ++n) {
        const int d  = n * 16 + ln;
        const int cc = (ks * 4 + q) ^ (d & 7);
        bv[n] = *(const bf16x8*)(lVT + d * 128 + cc * 8);
      }
#pragma unroll
      for (int i = 0; i < 2; ++i) {
        const int m = wave * 32 + i * 16 + ln;
        const bf16x8 ap = *(const bf16x8*)(lP + m * 128 + (((ks * 4 + q) ^ (m & 7)) << 3));
#pragma unroll
        for (int n = 0; n < 4; ++n)
          accO[i][n] = __builtin_amdgcn_mfma_f32_16x16x32_bf16(ap, bv[n], accO[i][n], 0, 0, 0);
        accS[i] = __builtin_amdgcn_mfma_f32_16x16x32_bf16(ap, ones, accS[i], 0, 0, 0);
      }
    }
    __builtin_amdgcn_s_setprio(0);

    if (jt < 15) {
#pragma unroll
      for (int it = 0; it < 2; ++it) {
        vcur[it][0] = vnxt[it][0];
        vcur[it][1] = vnxt[it][1];
      }
    }
  }

  // ---- normalize and store O over the Q slot.
#pragma unroll
  for (int i = 0; i < 2; ++i) {
#pragma unroll
    for (int r = 0; r < 4; ++r) {
      const int row = wave * 32 + i * 16 + q * 4 + r;
      const float rcp = 1.0f / fmaxf(accS[i][r], 1e-20f);
#pragma unroll
      for (int n = 0; n < 4; ++n) {
        const int col = n * 16 + ln;
        Qbase[(size_t)row * 3072 + col] = (bf16_t)(accO[i][n][r] * rcp);
      }
    }
  }
}

// ---------------------------------------------------------------------------
extern "C" void kernel_launch(void* const* d_in, const int* in_sizes, int n_in,
                              void* d_out, int out_size, void* d_ws, size_t ws_size,
                              hipStream_t stream)
{
  const float* x     = (const float*)d_in[0];  // [4,2048,1024] fp32
  const float* w_qkv = (const float*)d_in[1];  // [3072,1024]   fp32
  const float* w_out = (const float*)d_in[2];  // [1024,1024]   fp32
  const float* b_out = (const float*)d_in[3];  // [1024]        fp32
  float* out = (float*)d_out;                  // [4,2048,1024] fp32

  // ws layout (75.5 MB total)
  bf16_t* qkv    = (bf16_t*)d_ws;                       // 8192*3072
  bf16_t* xb     = qkv    + (size_t)8192 * 3072;        // 8192*1024
  bf16_t* wqkvb  = xb     + (size_t)8192 * 1024;        // 3072*1024
  bf16_t* woutb  = wqkvb  + (size_t)3072 * 1024;        // 1024*1024

  // softmax scale (1/32) * log2(e), folded into Q by GEMM1's epilogue
  const float qs = 0.04508422f;

  // 0) pre-convert all fp32 operands to bf16 in one launch
  cvt_all<<<dim3(6144), dim3(256), 0, stream>>>(x, xb, w_qkv, wqkvb, w_out, woutb);

  // 1) qkv = xb @ wqkvb^T   (Q cols pre-scaled in f32 by epilogue)
  //    grid: 64 mt x 12 nt = 768 blocks (BN=256)
  gemm_bt<false><<<dim3(768), dim3(256), 0, stream>>>(
      xb, wqkvb, nullptr, qkv, 8192, 3072, 1024, 1024, 1024, qs);
  // 2) attention in-place: O overwrites the Q slot of qkv (bf16)
  attn_kernel<<<dim3(1024), dim3(256), 0, stream>>>(qkv);
  // 3) out = O @ woutb^T + b_out  (bf16 in, fp32 out; O strided at lda=3072)
  //    grid: 64 mt x 4 nt = 256 blocks
  gemm_bt<true><<<dim3(256), dim3(256), 0, stream>>>(
      qkv, woutb, b_out, out, 8192, 1024, 1024, 3072, 0, 1.0f);
}

// Round 11
// 259.037 us; speedup vs baseline: 1.0322x; 1.0322x over previous
//
#include <hip/hip_runtime.h>

typedef __bf16 bf16_t;
typedef __bf16 bf16x2 __attribute__((ext_vector_type(2)));
typedef __bf16 bf16x4 __attribute__((ext_vector_type(4)));
typedef __bf16 bf16x8 __attribute__((ext_vector_type(8)));
typedef float floatx4 __attribute__((ext_vector_type(4)));

// async 16B/lane global->LDS (bf16 operands only). Dest = wave-uniform base + lane*16.
__device__ __forceinline__ void gll16(const void* g, void* l) {
  __builtin_amdgcn_global_load_lds(
      (const __attribute__((address_space(1))) void*)g,
      (__attribute__((address_space(3))) void*)l, 16, 0, 0);
}

__device__ __forceinline__ bf16x8 cvt8(const float4 a, const float4 b) {
  bf16x8 v;
  v[0] = (bf16_t)a.x; v[1] = (bf16_t)a.y; v[2] = (bf16_t)a.z; v[3] = (bf16_t)a.w;
  v[4] = (bf16_t)b.x; v[5] = (bf16_t)b.y; v[6] = (bf16_t)b.z; v[7] = (bf16_t)b.w;
  return v;
}

// K-row permutation: LDS row u (within a 32-token block) receives global token
// q*8 + e*4 + t where u = e*16 + q*4 + t. Result: after S^T MFMA on the two
// 16-tiles of a 32-chunk, lane q holds exactly toks q*8..q*8+7 = the PV
// A-fragment -> P stays in registers (no lP round-trip, no cross-lane ops).
__device__ __forceinline__ int permk(int r) {
  const int u = r & 31;
  return (r & ~31) + (((u >> 2) & 3) << 3) + ((u >> 4) << 2) + (u & 3);
}

// ---------------------------------------------------------------------------
// fp32 -> bf16 for all three operands in ONE launch.
// ---------------------------------------------------------------------------
__global__ __launch_bounds__(256)
void cvt_all(const float* __restrict__ x,  bf16_t* __restrict__ xb,
             const float* __restrict__ wq, bf16_t* __restrict__ wqb,
             const float* __restrict__ wo, bf16_t* __restrict__ wob)
{
  const int bid = blockIdx.x;
  const float* s;
  bf16_t* d;
  int i;
  if (bid < 4096)      { s = x;  d = xb;  i = bid * 256 + threadIdx.x; }
  else if (bid < 5632) { s = wq; d = wqb; i = (bid - 4096) * 256 + threadIdx.x; }
  else                 { s = wo; d = wob; i = (bid - 5632) * 256 + threadIdx.x; }
  const float4 a = ((const float4*)s)[2 * i];
  const float4 b = ((const float4*)s)[2 * i + 1];
  *(bf16x8*)(d + (size_t)i * 8) = cvt8(a, b);
}

// ---------------------------------------------------------------------------
// GEMM: C[M,Nf] = A[M,K] * W[Nf,K]^T (+bias), fp32 accum, bf16 MFMA.
// Reverted to the round-8 build (best passing GEMM: counted-vmcnt 3-buf,
// BK=32, 128x128 tile, 3 blocks/CU). Four structures measured identical ->
// GEMM left alone this round; attn is the attack surface.
// ---------------------------------------------------------------------------
template<bool C32>
__global__ __launch_bounds__(256, 3)
void gemm_bt(const bf16_t* __restrict__ Ab, const bf16_t* __restrict__ Wb,
             const float* __restrict__ bias, void* __restrict__ Cv,
             int M, int Nf, int K, int lda, int qcols, float qscale)
{
  __shared__ __align__(16) bf16_t lA[3][128 * 32];
  __shared__ __align__(16) bf16_t lB[3][128 * 32];

  const int tid  = threadIdx.x;
  const int wave = tid >> 6;
  const int lane = tid & 63;
  const int q    = lane >> 4;
  const int ln   = lane & 15;
  const int wm   = wave >> 1, wn = wave & 1;

  const int x     = blockIdx.x & 7;
  const int local = blockIdx.x >> 3;
  const int mt = x * 8 + (local & 7);
  const int nt = local >> 3;
  const int m0 = mt << 7, n0 = nt << 7;

  const int kiters = K >> 5;

  auto stage = [&](int buf, int k0s) {
#pragma unroll
    for (int tt = 0; tt < 2; ++tt) {
      const int rbase = tt * 64 + wave * 16;
      const int r  = rbase + (lane >> 2);
      const int gc = (lane & 3) ^ ((r >> 1) & 3);
      gll16(Ab + (size_t)(m0 + r) * lda + k0s + gc * 8, lA[buf] + rbase * 32);
      gll16(Wb + (size_t)(n0 + r) * K   + k0s + gc * 8, lB[buf] + rbase * 32);
    }
  };

  floatx4 acc[4][4] = {};

  stage(0, 0);
  stage(1, 32);

  for (int t = 0; t < kiters; ++t) {
    const int buf = t % 3;

    if (t + 1 < kiters) {
      asm volatile("s_waitcnt vmcnt(4)" ::: "memory");
    } else {
      asm volatile("s_waitcnt vmcnt(0)" ::: "memory");
    }
    __builtin_amdgcn_sched_barrier(0);
    __builtin_amdgcn_s_barrier();
    __builtin_amdgcn_sched_barrier(0);

    bf16x8 af[4], bfr[4];
#pragma unroll
    for (int i = 0; i < 4; ++i) {
      const int r = wm * 64 + i * 16 + ln;
      af[i] = *(const bf16x8*)(lA[buf] + r * 32 + (q ^ ((r >> 1) & 3)) * 8);
    }
#pragma unroll
    for (int j = 0; j < 4; ++j) {
      const int r = wn * 64 + j * 16 + ln;
      bfr[j] = *(const bf16x8*)(lB[buf] + r * 32 + (q ^ ((r >> 1) & 3)) * 8);
    }
    __builtin_amdgcn_s_setprio(1);
#pragma unroll
    for (int i = 0; i < 4; ++i)
#pragma unroll
      for (int j = 0; j < 4; ++j)
        acc[i][j] = __builtin_amdgcn_mfma_f32_16x16x32_bf16(af[i], bfr[j], acc[i][j], 0, 0, 0);
    __builtin_amdgcn_s_setprio(0);

    if (t + 2 < kiters) stage((t + 2) % 3, (t + 2) << 5);
  }

  // epilogue: C/D layout col=lane&15, row=(lane>>4)*4+reg
#pragma unroll
  for (int j = 0; j < 4; ++j) {
    const int col = n0 + wn * 64 + j * 16 + ln;
    const float bv = bias ? bias[col] : 0.0f;
    const float sc = (col < qcols) ? qscale : 1.0f;
#pragma unroll
    for (int i = 0; i < 4; ++i) {
      const int row = m0 + wm * 64 + i * 16 + q * 4;
#pragma unroll
      for (int r = 0; r < 4; ++r) {
        const float val = acc[i][j][r] * sc + bv;
        if constexpr (C32)
          ((float*)Cv)[(size_t)(row + r) * Nf + col] = val;
        else
          ((bf16_t*)Cv)[(size_t)(row + r) * Nf + col] = (bf16_t)val;
      }
    }
  }
}

// ---------------------------------------------------------------------------
// Attention, in-place on bf16 qkv (Q pre-scaled by softmax scale * log2e).
// Round-19: in-register P via permuted K staging.
//  - K staged with permk() on the GLOBAL source row (LDS linear, m173
//    pattern): S^T output lands so lane q holds toks q*8..q*8+7 of each
//    32-chunk = the PV A-fragment. lP (32 KB) deleted; P never in LDS.
//  - Each wave computes partial O over its wn tok-half for wm's 64 m-rows;
//    bv reads halve (wave reads only its half of V^T). Cross-wn partial sum
//    once at epilogue through the freed lK buffer.
//  - LDS 80 -> 48 KiB; per-wave-iter LDS: 32->16 b128 reads, -16 b64 writes.
// ---------------------------------------------------------------------------
__global__ __launch_bounds__(256, 2)
void attn_kernel(bf16_t* __restrict__ qkv)
{
  __shared__ __align__(16) bf16_t lK[2][128 * 64]; // K dbuf, rows perm'd per 32-block
  __shared__ __align__(16) bf16_t lVT[64 * 128];   // V^T [d][tok] chunk^(d&7); head = Q staging

  const int tid  = threadIdx.x;
  const int wave = tid >> 6;
  const int lane = tid & 63;
  const int q  = lane >> 4;
  const int ln = lane & 15;
  const int wm = wave >> 1, wn = wave & 1;

  // XCD swizzle: hw%8 = XCD; each XCD gets 128 consecutive work-ids
  const int hw = blockIdx.x;
  const int w  = (hw & 7) * 128 + (hw >> 3);
  const int qt = w & 15;
  const int h  = (w >> 4) & 15;
  const int b  = w >> 8;

  bf16_t* Qbase = qkv + (size_t)(b * 2048 + qt * 128) * 3072 + h * 64;  // also O dest
  const bf16_t* Kbase = qkv + (size_t)(b * 2048) * 3072 + 1024 + h * 64;
  const bf16_t* Vbase = qkv + (size_t)(b * 2048) * 3072 + 2048 + h * 64;

  // ---- prologue: Q -> lVT head (flat [128][64], chunk^(r&7)); K[0] -> lK[0]
  //      with permuted global rows (LDS row r gets token permk(r)).
#pragma unroll
  for (int t = 0; t < 4; ++t) {
    const int rbase = t * 32 + wave * 8;
    const int r  = rbase + (lane >> 3);
    const int gc = (lane & 7) ^ (r & 7);
    gll16(Qbase + (size_t)r * 3072 + gc * 8, lVT + rbase * 64);
    gll16(Kbase + (size_t)permk(r) * 3072 + gc * 8, lK[0] + rbase * 64);
  }
  __syncthreads();

  bf16x8 qf[4][2];  // Q[m][d] fragments (MFMA B-operand); m = wm*64 + n*16 + ln
#pragma unroll
  for (int i = 0; i < 4; ++i) {
    const int r = wm * 64 + i * 16 + ln;
#pragma unroll
    for (int kt = 0; kt < 2; ++kt) {
      const int c = (kt * 4 + q) ^ (r & 7);
      qf[i][kt] = *(const bf16x8*)(lVT + r * 64 + c * 8);
    }
  }
  // (iter-0's top barrier orders qf reads vs lVT reuse by the V scatter)

  // V[0] into regs (token pair 2*lane, 2*lane+1; d-chunks wave + it*4)
  bf16x8 vcur[2][2], vnxt[2][2];
#pragma unroll
  for (int it = 0; it < 2; ++it) {
    const bf16_t* src = Vbase + (size_t)(2 * lane) * 3072 + (wave + it * 4) * 8;
    vcur[it][0] = *(const bf16x8*)src;
    vcur[it][1] = *(const bf16x8*)(src + 3072);
  }

  floatx4 accO[4][4] = {};  // [m-tile n][d-tile nd]; partial over wn's 64 toks
  floatx4 accS[4] = {};     // partial rowsums

  bf16x8 ones;
#pragma unroll
  for (int j = 0; j < 8; ++j) ones[j] = (bf16_t)1.0f;

  for (int jt = 0; jt < 16; ++jt) {
    const bf16_t* lKc = lK[jt & 1];
    bf16_t*       lKn = lK[(jt & 1) ^ 1];

    // syncA: prev-iter PV reads of lVT done; lK[cur] DMA + vcur loads landed
    // (in-order vmcnt chain: vcur reg-loads issued after the K DMAs, and the
    // vcur=vnxt copy at loop end forces the wait).
    __syncthreads();

    // scatter vcur -> lVT[d][tok], tok-chunk ch = (tok>>3)^(d&7)
#pragma unroll
    for (int it = 0; it < 2; ++it) {
      const int c = wave + it * 4;
#pragma unroll
      for (int j = 0; j < 8; ++j) {
        const int d  = c * 8 + j;
        const int ch = (lane >> 2) ^ (d & 7);
        bf16x2 pr;
        pr[0] = vcur[it][0][j];
        pr[1] = vcur[it][1][j];
        *(bf16x2*)(lVT + d * 128 + ch * 8 + ((2 * lane) & 7)) = pr;
      }
    }

    // ---- prefetch tile jt+1: K -> lK[nxt] (perm'd), V -> regs.
    if (jt < 15) {
      const int j0n = (jt + 1) * 128;
#pragma unroll
      for (int t = 0; t < 4; ++t) {
        const int rbase = t * 32 + wave * 8;
        const int r  = rbase + (lane >> 3);
        const int gc = (lane & 7) ^ (r & 7);
        gll16(Kbase + (size_t)(j0n + permk(r)) * 3072 + gc * 8, lKn + rbase * 64);
      }
#pragma unroll
      for (int it = 0; it < 2; ++it) {
        const bf16_t* src = Vbase + (size_t)(j0n + 2 * lane) * 3072 + (wave + it * 4) * 8;
        vnxt[it][0] = *(const bf16x8*)src;
        vnxt[it][1] = *(const bf16x8*)(src + 3072);
      }
    }

    // ---- S^T = K Q^T, P packed directly into A-fragments ap[c][n].
    // Wave's toks = wn*64 + c*32 + (q*8..q*8+7) after the K-row permutation.
    bf16x8 ap[2][4];
    __builtin_amdgcn_s_setprio(1);
#pragma unroll
    for (int c = 0; c < 2; ++c) {
#pragma unroll
      for (int e = 0; e < 2; ++e) {
        const int rb = wn * 64 + (c * 2 + e) * 16 + ln;
        const bf16x8 kf0 = *(const bf16x8*)(lKc + rb * 64 + ((q)     ^ (rb & 7)) * 8);
        const bf16x8 kf1 = *(const bf16x8*)(lKc + rb * 64 + ((4 + q) ^ (rb & 7)) * 8);
#pragma unroll
        for (int n = 0; n < 4; ++n) {
          floatx4 st = {0.0f, 0.0f, 0.0f, 0.0f};
          st = __builtin_amdgcn_mfma_f32_16x16x32_bf16(kf0, qf[n][0], st, 0, 0, 0);
          st = __builtin_amdgcn_mfma_f32_16x16x32_bf16(kf1, qf[n][1], st, 0, 0, 0);
          // lane holds S^T[tok = wn*64 + c*32 + q*8 + e*4 + r][m = wm*64+n*16+ln]
#pragma unroll
          for (int r4 = 0; r4 < 4; ++r4)
            ap[c][n][e * 4 + r4] = (bf16_t)__builtin_amdgcn_exp2f(st[r4]);
        }
      }
    }
    __builtin_amdgcn_s_setprio(0);

    // syncB: lVT scatter visible to all waves before PV reads.
    __syncthreads();

    // ---- O_partial += P * V ; rowsum_partial += P * 1  (wave's tok-half)
    __builtin_amdgcn_s_setprio(1);
#pragma unroll
    for (int c = 0; c < 2; ++c) {
      bf16x8 bv[4];
#pragma unroll
      for (int nd = 0; nd < 4; ++nd) {
        const int d  = nd * 16 + ln;
        const int cc = (wn * 8 + c * 4 + q) ^ (d & 7);
        bv[nd] = *(const bf16x8*)(lVT + d * 128 + cc * 8);
      }
#pragma unroll
      for (int n = 0; n < 4; ++n) {
#pragma unroll
        for (int nd = 0; nd < 4; ++nd)
          accO[n][nd] = __builtin_amdgcn_mfma_f32_16x16x32_bf16(ap[c][n], bv[nd], accO[n][nd], 0, 0, 0);
        accS[n] = __builtin_amdgcn_mfma_f32_16x16x32_bf16(ap[c][n], ones, accS[n], 0, 0, 0);
      }
    }
    __builtin_amdgcn_s_setprio(0);

    if (jt < 15) {
#pragma unroll
      for (int it = 0; it < 2; ++it) {
        vcur[it][0] = vnxt[it][0];
        vcur[it][1] = vnxt[it][1];
      }
    }
  }

  // ---- epilogue: cross-wn partial sum through freed lK, normalize, store.
  // accO lane layout: m = n*16 + q*4 + r (wave covers wm*64..+64), d = nd*16+ln.
  float* red  = (float*)lK;   // 8192 f32 = 32 KB: [wm][m 0..63][d 0..63]
  float* redS = (float*)lVT;  // 128 f32 rowsums

  if (wn == 1) {
#pragma unroll
    for (int n = 0; n < 4; ++n)
#pragma unroll
      for (int nd = 0; nd < 4; ++nd)
#pragma unroll
        for (int r4 = 0; r4 < 4; ++r4)
          red[wm * 4096 + (n * 16 + q * 4 + r4) * 64 + nd * 16 + ln] = accO[n][nd][r4];
  }
  __syncthreads();  // red ready; all PV done -> lVT reusable
  if (wn == 1 && ln == 0) {
#pragma unroll
    for (int n = 0; n < 4; ++n)
#pragma unroll
      for (int r4 = 0; r4 < 4; ++r4)
        redS[wm * 64 + n * 16 + q * 4 + r4] = accS[n][r4];
  }
  __syncthreads();  // redS ready
  if (wn == 0) {
#pragma unroll
    for (int n = 0; n < 4; ++n) {
#pragma unroll
      for (int r4 = 0; r4 < 4; ++r4) {
        const int m = n * 16 + q * 4 + r4;
        const float s = accS[n][r4] + redS[wm * 64 + m];
        const float rcp = 1.0f / fmaxf(s, 1e-20f);
#pragma unroll
        for (int nd = 0; nd < 4; ++nd) {
          const float o = accO[n][nd][r4] + red[wm * 4096 + m * 64 + nd * 16 + ln];
          Qbase[(size_t)(wm * 64 + m) * 3072 + nd * 16 + ln] = (bf16_t)(o * rcp);
        }
      }
    }
  }
}

// ---------------------------------------------------------------------------
extern "C" void kernel_launch(void* const* d_in, const int* in_sizes, int n_in,
                              void* d_out, int out_size, void* d_ws, size_t ws_size,
                              hipStream_t stream)
{
  const float* x     = (const float*)d_in[0];  // [4,2048,1024] fp32
  const float* w_qkv = (const float*)d_in[1];  // [3072,1024]   fp32
  const float* w_out = (const float*)d_in[2];  // [1024,1024]   fp32
  const float* b_out = (const float*)d_in[3];  // [1024]        fp32
  float* out = (float*)d_out;                  // [4,2048,1024] fp32

  // ws layout (75.5 MB total)
  bf16_t* qkv    = (bf16_t*)d_ws;                       // 8192*3072
  bf16_t* xb     = qkv    + (size_t)8192 * 3072;        // 8192*1024
  bf16_t* wqkvb  = xb     + (size_t)8192 * 1024;        // 3072*1024
  bf16_t* woutb  = wqkvb  + (size_t)3072 * 1024;        // 1024*1024

  // softmax scale (1/32) * log2(e), folded into Q by GEMM1's epilogue
  const float qs = 0.04508422f;

  // 0) pre-convert all fp32 operands to bf16 in one launch
  cvt_all<<<dim3(6144), dim3(256), 0, stream>>>(x, xb, w_qkv, wqkvb, w_out, woutb);

  // 1) qkv = xb @ wqkvb^T   (Q cols pre-scaled in f32 by epilogue)
  gemm_bt<false><<<dim3(64 * 24), dim3(256), 0, stream>>>(
      xb, wqkvb, nullptr, qkv, 8192, 3072, 1024, 1024, 1024, qs);
  // 2) attention in-place: O overwrites the Q slot of qkv (bf16)
  attn_kernel<<<dim3(1024), dim3(256), 0, stream>>>(qkv);
  // 3) out = O @ woutb^T + b_out  (bf16 in, fp32 out; O strided at lda=3072)
  gemm_bt<true><<<dim3(64 * 8), dim3(256), 0, stream>>>(
      qkv, woutb, b_out, out, 8192, 1024, 1024, 3072, 0, 1.0f);
}